// Round 10
// baseline (384.907 us; speedup 1.0000x reference)
//
#include <hip/hip_runtime.h>
#include <hip/hip_bf16.h>

// AttentionDownsample: B=256, N=196(14x14), NQ=49(7x7 stride2), IN=384,
// HEADS=12, KEY=16, VAL=32, KV=576, OUT=512.
// Contract (verified R8): inputs fp32, bias_idxs int32, output fp32.
// R10: x + weights pre-cast to bf16 once (kills 9x fp32 re-fetch + per-tile
// cvt in kv GEMM, R9's top cost); all GEMMs stage pure bf16; kv+attn in 4
// chunks of 64 batches to fit 68.9 MB workspace (known-safe ~72.7 MB).

typedef __bf16 bf16;
typedef float f32x4 __attribute__((ext_vector_type(4)));
typedef __bf16 bf16x8 __attribute__((ext_vector_type(8)));
typedef __bf16 bf16x4 __attribute__((ext_vector_type(4)));

// per-(b,h) kv2 block: k [196][16] el at +0, vT [32][196] el at +6272 B
#define KV2_BLK 18816
#define KV2_VOFF 6272
#define Q2_BLK 1568

// ---------------------------------------------------------------------------
__global__ void cast_kernel(const float* __restrict__ src, bf16* __restrict__ dst, long n) {
  long i = ((long)blockIdx.x * 256 + threadIdx.x) * 8;
  if (i + 8 <= n) {
    f32x4 lo = *(const f32x4*)(src + i), hi = *(const f32x4*)(src + i + 4);
    bf16x8 t;
    t[0]=(bf16)lo[0]; t[1]=(bf16)lo[1]; t[2]=(bf16)lo[2]; t[3]=(bf16)lo[3];
    t[4]=(bf16)hi[0]; t[5]=(bf16)hi[1]; t[6]=(bf16)hi[2]; t[7]=(bf16)hi[3];
    *(bf16x8*)(dst + i) = t;
  }
}

// ---------------------------------------------------------------------------
__global__ void prep_kernel(const float* kv_g, const float* kv_b, const float* kv_m, const float* kv_v,
                            const float* q_g,  const float* q_b,  const float* q_m,  const float* q_v,
                            const float* p_g,  const float* p_b,  const float* p_m,  const float* p_v,
                            float* scbuf) {
  int i = blockIdx.x * 256 + threadIdx.x;
  const float *g, *bb, *mm, *vv;
  float *sc, *sh;
  int c;
  if (i < 576)        { c = i;       g = kv_g; bb = kv_b; mm = kv_m; vv = kv_v; sc = scbuf;        sh = scbuf + 576;  }
  else if (i < 768)   { c = i - 576; g = q_g;  bb = q_b;  mm = q_m;  vv = q_v;  sc = scbuf + 1152; sh = scbuf + 1344; }
  else if (i < 1280)  { c = i - 768; g = p_g;  bb = p_b;  mm = p_m;  vv = p_v;  sc = scbuf + 1536; sh = scbuf + 2048; }
  else return;
  float sv = g[c] * rsqrtf(vv[c] + 1e-5f);
  sc[c] = sv;
  sh[c] = bb[c] - mm[c] * sv;
}

// ---------------------------------------------------------------------------
__global__ void bias_kernel(const float* biases, const int* idxs, float* biasp) {
  int i = blockIdx.x * 256 + threadIdx.x;
  if (i < 12 * 49 * 196) {
    int h = i / (49 * 196);
    int rem = i - h * (49 * 196);
    biasp[i] = biases[h * 196 + idxs[rem]];
  }
}

// ---------------------------------------------------------------------------
// GEMM C = A[M,384] @ W[N,384]^T, BN epilogue. A, W bf16.
// Tile 128x64, 128 threads (2 waves), wave does 64x64 via 4x4 mfma 16x16x32.
// EPI: 0 = plain fp32 C (pj) | 1 = kv scatter (chunk-local b) | 2 = q scatter.
// GATHER: A-row m -> x row b*196 + (qq/7)*28 + (qq%7)*2.
template<int EPI, bool GATHER>
__global__ __launch_bounds__(128)
void gemm_bn_kernel(const bf16* __restrict__ A, const bf16* __restrict__ W,
                    const float* __restrict__ sc, const float* __restrict__ sh,
                    char* __restrict__ out, int N) {
  __shared__ __attribute__((aligned(16))) bf16 As[128 * 32];
  __shared__ __attribute__((aligned(16))) bf16 Ws[64 * 32];
  const int tid  = threadIdx.x;
  const int lane = tid & 63;
  const int wid  = tid >> 6;
  const int m0 = blockIdx.y * 128;
  const int n0 = blockIdx.x * 64;
  const int c8  = tid & 3;
  const int rbs = tid >> 2;

  long eA[4]; int lAoff[4];
#pragma unroll
  for (int rr = 0; rr < 4; ++rr) {
    int r = rr * 32 + rbs;
    long arow;
    if (GATHER) {
      int m = m0 + r;
      int b = m / 49;
      int qq = m - b * 49;
      arow = (long)b * 196 + (qq / 7) * 28 + (qq % 7) * 2;
    } else {
      arow = m0 + r;
    }
    eA[rr] = arow * 384 + c8 * 8;
    lAoff[rr] = r * 32 + c8 * 8;
  }
  long eW[2]; int lWoff[2];
#pragma unroll
  for (int rr = 0; rr < 2; ++rr) {
    int r = rr * 32 + rbs;
    eW[rr] = (long)(n0 + r) * 384 + c8 * 8;
    lWoff[rr] = r * 32 + c8 * 8;
  }

  f32x4 acc[4][4] = {};
  const int mrow = lane & 15;
  const int quad = lane >> 4;

  for (int k0 = 0; k0 < 384; k0 += 32) {
    bf16x8 ta[4], tw[2];
#pragma unroll
    for (int rr = 0; rr < 4; ++rr) ta[rr] = *(const bf16x8*)(A + eA[rr] + k0);
#pragma unroll
    for (int rr = 0; rr < 2; ++rr) tw[rr] = *(const bf16x8*)(W + eW[rr] + k0);
    __syncthreads();
#pragma unroll
    for (int rr = 0; rr < 4; ++rr) *(bf16x8*)(As + lAoff[rr]) = ta[rr];
#pragma unroll
    for (int rr = 0; rr < 2; ++rr) *(bf16x8*)(Ws + lWoff[rr]) = tw[rr];
    __syncthreads();

    bf16x8 af[4], bw[4];
#pragma unroll
    for (int mi = 0; mi < 4; ++mi)
      af[mi] = *(const bf16x8*)(As + (wid * 64 + mi * 16 + mrow) * 32 + quad * 8);
#pragma unroll
    for (int ni = 0; ni < 4; ++ni)
      bw[ni] = *(const bf16x8*)(Ws + (ni * 16 + mrow) * 32 + quad * 8);
#pragma unroll
    for (int mi = 0; mi < 4; ++mi)
#pragma unroll
      for (int ni = 0; ni < 4; ++ni)
        acc[mi][ni] = __builtin_amdgcn_mfma_f32_16x16x32_bf16(af[mi], bw[ni], acc[mi][ni], 0, 0, 0);
  }

  // epilogue: C/D layout col=lane&15, row=quad*4+reg (m89-verified)
#pragma unroll
  for (int ni = 0; ni < 4; ++ni) {
    int col = n0 + ni * 16 + mrow;
    float s = sc[col], t = sh[col];
    int h = 0, dd = 0;
    if (EPI == 1) { h = col / 48; dd = col - h * 48; }
    if (EPI == 2) { h = col >> 4; dd = col & 15; }
#pragma unroll
    for (int mi = 0; mi < 4; ++mi) {
#pragma unroll
      for (int reg = 0; reg < 4; ++reg) {
        int m = m0 + wid * 64 + mi * 16 + quad * 4 + reg;
        float y = acc[mi][ni][reg] * s + t;
        if (EPI == 0) {
          ((float*)out)[(long)m * N + col] = y;
        } else if (EPI == 1) {
          int b = m / 196, j = m - b * 196;   // b chunk-local
          char* base = out + ((long)(b * 12 + h)) * KV2_BLK;
          if (dd < 16) ((bf16*)base)[j * 16 + dd] = (bf16)y;
          else ((bf16*)(base + KV2_VOFF))[(dd - 16) * 196 + j] = (bf16)y;
        } else {
          int b = m / 49, qq = m - b * 49;
          ((bf16*)(out + ((long)(b * 12 + h)) * Q2_BLK))[qq * 16 + dd] = (bf16)y;
        }
      }
    }
  }
}

// ---------------------------------------------------------------------------
// Fused MFMA attention, one block per (b,h) of a 64-batch chunk. 256 threads.
// LDS (42 KB): [vT 14336][q 4096][k 13312]; P (28672) overlays q+k after QK.
__global__ __launch_bounds__(256)
void attn_kernel(const char* __restrict__ kv2, const char* __restrict__ qb2,
                 const float* __restrict__ biasp, bf16* __restrict__ aout,
                 int b0) {
  __shared__ __attribute__((aligned(16))) char smem[43008];
  bf16* vT_s = (bf16*)smem;            // [32][224]
  bf16* q_s  = (bf16*)(smem + 14336);  // [64][32]
  bf16* k_s  = (bf16*)(smem + 18432);  // [208][32]
  bf16* P_s  = (bf16*)(smem + 14336);  // [64][224] overlay (post-QK)

  const int bh = blockIdx.x;
  const int bl = bh / 12;              // chunk-local batch
  const int h = bh - bl * 12;
  const int bg = b0 + bl;              // global batch
  const int tid  = threadIdx.x;
  const int lane = tid & 63;
  const int wid  = tid >> 6;

  const bf16* ksrc = (const bf16*)(kv2 + (long)bh * KV2_BLK);
  const bf16* vsrc = (const bf16*)(kv2 + (long)bh * KV2_BLK + KV2_VOFF);
  const bf16* qsrc = (const bf16*)(qb2 + (long)(bg * 12 + h) * Q2_BLK);

  {
    int row = tid >> 2, cg = tid & 3;
    bf16x8 z = {};
    *(bf16x8*)(q_s + row * 32 + cg * 8) =
        (row < 49 && cg < 2) ? *(const bf16x8*)(qsrc + row * 16 + cg * 8) : z;
    for (int i = tid; i < 832; i += 256) {
      int r = i >> 2, c = i & 3;
      *(bf16x8*)(k_s + r * 32 + c * 8) =
          (r < 196 && c < 2) ? *(const bf16x8*)(ksrc + r * 16 + c * 8) : z;
    }
    bf16x4 z4 = {};
    for (int i = tid; i < 1792; i += 256) {
      int r = i / 56, c = i - r * 56;
      *(bf16x4*)(vT_s + r * 224 + c * 4) =
          (c < 49) ? *(const bf16x4*)(vsrc + r * 196 + c * 4) : z4;
    }
  }
  __syncthreads();

  const int mrow = lane & 15;
  const int quad = lane >> 4;

  // QK^T: 13 n-tiles of 16 keys
  f32x4 s[13];
  bf16x8 aq = *(const bf16x8*)(q_s + (wid * 16 + mrow) * 32 + quad * 8);
#pragma unroll
  for (int jt = 0; jt < 13; ++jt) {
    bf16x8 bk = *(const bf16x8*)(k_s + (jt * 16 + mrow) * 32 + quad * 8);
    f32x4 z = {};
    s[jt] = __builtin_amdgcn_mfma_f32_16x16x32_bf16(aq, bk, z, 0, 0, 0);
  }

  const int rbase = wid * 16 + quad * 4;
#pragma unroll
  for (int jt = 0; jt < 13; ++jt) {
    int c = jt * 16 + mrow;
#pragma unroll
    for (int reg = 0; reg < 4; ++reg) {
      int r = rbase + reg;
      float v = s[jt][reg] * 0.25f;
      if (c < 196) {
        if (r < 49) v += biasp[((long)h * 49 + r) * 196 + c];
      } else {
        v = -1e30f;
      }
      s[jt][reg] = v;
    }
  }
  float mx[4], sm[4];
#pragma unroll
  for (int reg = 0; reg < 4; ++reg) {
    float m = -1e30f;
#pragma unroll
    for (int jt = 0; jt < 13; ++jt) m = fmaxf(m, s[jt][reg]);
    m = fmaxf(m, __shfl_xor(m, 1));
    m = fmaxf(m, __shfl_xor(m, 2));
    m = fmaxf(m, __shfl_xor(m, 4));
    m = fmaxf(m, __shfl_xor(m, 8));
    mx[reg] = m;
  }
#pragma unroll
  for (int jt = 0; jt < 13; ++jt) {
    int c = jt * 16 + mrow;
#pragma unroll
    for (int reg = 0; reg < 4; ++reg)
      s[jt][reg] = (c < 196) ? __expf(s[jt][reg] - mx[reg]) : 0.0f;
  }
#pragma unroll
  for (int reg = 0; reg < 4; ++reg) {
    float t = 0.0f;
#pragma unroll
    for (int jt = 0; jt < 13; ++jt) t += s[jt][reg];
    t += __shfl_xor(t, 1);
    t += __shfl_xor(t, 2);
    t += __shfl_xor(t, 4);
    t += __shfl_xor(t, 8);
    sm[reg] = 1.0f / t;
  }

  __syncthreads();  // all waves done with q_s/k_s before P overlay writes

  bf16* Pw = P_s + wid * 16 * 224;
#pragma unroll
  for (int jt = 0; jt < 13; ++jt) {
#pragma unroll
    for (int reg = 0; reg < 4; ++reg)
      Pw[(quad * 4 + reg) * 224 + jt * 16 + mrow] = (bf16)(s[jt][reg] * sm[reg]);
  }
#pragma unroll
  for (int reg = 0; reg < 4; ++reg)
    Pw[(quad * 4 + reg) * 224 + 208 + mrow] = (bf16)0.0f;

  f32x4 o[2] = {};
#pragma unroll
  for (int kk = 0; kk < 7; ++kk) {
    bf16x8 ap = *(const bf16x8*)(Pw + mrow * 224 + kk * 32 + quad * 8);
#pragma unroll
    for (int nt = 0; nt < 2; ++nt) {
      bf16x8 bv = *(const bf16x8*)(vT_s + (nt * 16 + mrow) * 224 + kk * 32 + quad * 8);
      o[nt] = __builtin_amdgcn_mfma_f32_16x16x32_bf16(ap, bv, o[nt], 0, 0, 0);
    }
  }
#pragma unroll
  for (int nt = 0; nt < 2; ++nt) {
#pragma unroll
    for (int reg = 0; reg < 4; ++reg) {
      int r = rbase + reg;
      if (r < 49) {
        float x = o[nt][reg];
        float sil = x / (1.0f + __expf(-x));
        aout[((long)bg * 49 + r) * 384 + h * 32 + nt * 16 + mrow] = (bf16)sil;
      }
    }
  }
}

// ---------------------------------------------------------------------------
extern "C" void kernel_launch(void* const* d_in, const int* in_sizes, int n_in,
                              void* d_out, int out_size, void* d_ws, size_t ws_size,
                              hipStream_t stream) {
  const float* x      = (const float*)d_in[0];
  const float* kv_w   = (const float*)d_in[1];
  const float* q_w    = (const float*)d_in[6];
  const float* pj_w   = (const float*)d_in[11];
  const float* biases = (const float*)d_in[16];
  const int*   bidx   = (const int*)d_in[17];

  char* ws = (char*)d_ws;
  float* scbuf = (float*)ws;                  // 2560 f32
  float* biasp = (float*)(ws + 10256);        // (12,49,196) f32
  char*  qb2   = ws + 471296;                 // 3072 x 1568 B
  bf16*  aout  = (bf16*)(ws + 5288192);       // (12544,384) bf16
  bf16*  xb    = (bf16*)(ws + 14921984);      // (50176,384) bf16 = 38.5 MB
  bf16*  kvwb  = (bf16*)(ws + 53457152);      // (576,384) bf16
  bf16*  qwb   = (bf16*)(ws + 53899520);      // (192,384) bf16
  bf16*  pjwb  = (bf16*)(ws + 54046976);      // (512,384) bf16
  char*  kv2   = ws + 54440192;               // chunk: 768 x 18816 B (14.45 MB)
                                              // end: 68,890,880 B

  // casts
  cast_kernel<<<9408, 256, 0, stream>>>(x, xb, 19267584L);
  cast_kernel<<<108, 256, 0, stream>>>(kv_w, kvwb, 221184L);
  cast_kernel<<<36, 256, 0, stream>>>(q_w, qwb, 73728L);
  cast_kernel<<<96, 256, 0, stream>>>(pj_w, pjwb, 196608L);

  prep_kernel<<<5, 256, 0, stream>>>(
      (const float*)d_in[2],  (const float*)d_in[3],  (const float*)d_in[4],  (const float*)d_in[5],
      (const float*)d_in[7],  (const float*)d_in[8],  (const float*)d_in[9],  (const float*)d_in[10],
      (const float*)d_in[12], (const float*)d_in[13], (const float*)d_in[14], (const float*)d_in[15],
      scbuf);
  bias_kernel<<<451, 256, 0, stream>>>(biases, bidx, biasp);

  // q = BN(xq @ q_w^T): M=12544 gathered, N=192 -> per-(b,h) q blocks
  gemm_bn_kernel<2, true><<<dim3(3, 98), 128, 0, stream>>>(
      xb, qwb, scbuf + 1152, scbuf + 1344, qb2, 192);

  // kv + attention in 4 chunks of 64 batches
  for (int ch = 0; ch < 4; ++ch) {
    gemm_bn_kernel<1, false><<<dim3(9, 98), 128, 0, stream>>>(
        xb + (long)ch * 12544 * 384, kvwb, scbuf, scbuf + 576, kv2, 576);
    attn_kernel<<<768, 256, 0, stream>>>(kv2, qb2, biasp, aout, ch * 64);
  }

  // out = BN(silu_attn @ pj_w^T): M=12544, N=512, fp32 out
  gemm_bn_kernel<0, false><<<dim3(8, 98), 128, 0, stream>>>(
      aout, pjwb, scbuf + 1536, scbuf + 2048, (char*)d_out, 512);
}

// Round 11
// 339.636 us; speedup vs baseline: 1.1333x; 1.1333x over previous
//
#include <hip/hip_runtime.h>
#include <hip/hip_bf16.h>

// AttentionDownsample: B=256, N=196(14x14), NQ=49(7x7 stride2), IN=384,
// HEADS=12, KEY=16, VAL=32, KV=576, OUT=512.
// Contract (verified R8): inputs fp32, bias_idxs int32, output fp32.
// R11: ws_size is ~300MB (fill counters) -> de-chunked single kv GEMM +
// single attention; bf16 pre-casts kept; GEMM grids m-major (m = blockIdx.x)
// so same-A blocks are dispatch-adjacent -> A fetched once, W replicated
// (W is tiny). R9's 4x A-over-fetch (320MB vs 77MB) was XCD L2 replication.

typedef __bf16 bf16;
typedef float f32x4 __attribute__((ext_vector_type(4)));
typedef __bf16 bf16x8 __attribute__((ext_vector_type(8)));
typedef __bf16 bf16x4 __attribute__((ext_vector_type(4)));

// per-(b,h) kv2 block: k [196][16] el at +0, vT [32][196] el at +6272 B
#define KV2_BLK 18816
#define KV2_VOFF 6272
#define Q2_BLK 1568

// ---------------------------------------------------------------------------
__global__ void cast_kernel(const float* __restrict__ src, bf16* __restrict__ dst, long n) {
  long i = ((long)blockIdx.x * 256 + threadIdx.x) * 8;
  if (i + 8 <= n) {
    f32x4 lo = *(const f32x4*)(src + i), hi = *(const f32x4*)(src + i + 4);
    bf16x8 t;
    t[0]=(bf16)lo[0]; t[1]=(bf16)lo[1]; t[2]=(bf16)lo[2]; t[3]=(bf16)lo[3];
    t[4]=(bf16)hi[0]; t[5]=(bf16)hi[1]; t[6]=(bf16)hi[2]; t[7]=(bf16)hi[3];
    *(bf16x8*)(dst + i) = t;
  }
}

// ---------------------------------------------------------------------------
__global__ void prep_kernel(const float* kv_g, const float* kv_b, const float* kv_m, const float* kv_v,
                            const float* q_g,  const float* q_b,  const float* q_m,  const float* q_v,
                            const float* p_g,  const float* p_b,  const float* p_m,  const float* p_v,
                            float* scbuf) {
  int i = blockIdx.x * 256 + threadIdx.x;
  const float *g, *bb, *mm, *vv;
  float *sc, *sh;
  int c;
  if (i < 576)        { c = i;       g = kv_g; bb = kv_b; mm = kv_m; vv = kv_v; sc = scbuf;        sh = scbuf + 576;  }
  else if (i < 768)   { c = i - 576; g = q_g;  bb = q_b;  mm = q_m;  vv = q_v;  sc = scbuf + 1152; sh = scbuf + 1344; }
  else if (i < 1280)  { c = i - 768; g = p_g;  bb = p_b;  mm = p_m;  vv = p_v;  sc = scbuf + 1536; sh = scbuf + 2048; }
  else return;
  float sv = g[c] * rsqrtf(vv[c] + 1e-5f);
  sc[c] = sv;
  sh[c] = bb[c] - mm[c] * sv;
}

// ---------------------------------------------------------------------------
__global__ void bias_kernel(const float* biases, const int* idxs, float* biasp) {
  int i = blockIdx.x * 256 + threadIdx.x;
  if (i < 12 * 49 * 196) {
    int h = i / (49 * 196);
    int rem = i - h * (49 * 196);
    biasp[i] = biases[h * 196 + idxs[rem]];
  }
}

// ---------------------------------------------------------------------------
// GEMM C = A[M,384] @ W[N,384]^T, BN epilogue. A, W bf16.
// Tile 128x64, 128 threads (2 waves), wave does 64x64 via 4x4 mfma 16x16x32.
// GRID IS M-MAJOR: m0 = blockIdx.x*128, n0 = blockIdx.y*64 (XCD L2 locality).
// EPI: 0 = plain fp32 C (pj) | 1 = kv scatter | 2 = q scatter.
// GATHER: A-row m -> x row b*196 + (qq/7)*28 + (qq%7)*2.
template<int EPI, bool GATHER>
__global__ __launch_bounds__(128)
void gemm_bn_kernel(const bf16* __restrict__ A, const bf16* __restrict__ W,
                    const float* __restrict__ sc, const float* __restrict__ sh,
                    char* __restrict__ out, int N) {
  __shared__ __attribute__((aligned(16))) bf16 As[128 * 32];
  __shared__ __attribute__((aligned(16))) bf16 Ws[64 * 32];
  const int tid  = threadIdx.x;
  const int lane = tid & 63;
  const int wid  = tid >> 6;
  const int m0 = blockIdx.x * 128;   // m-major dispatch
  const int n0 = blockIdx.y * 64;
  const int c8  = tid & 3;
  const int rbs = tid >> 2;

  long eA[4]; int lAoff[4];
#pragma unroll
  for (int rr = 0; rr < 4; ++rr) {
    int r = rr * 32 + rbs;
    long arow;
    if (GATHER) {
      int m = m0 + r;
      int b = m / 49;
      int qq = m - b * 49;
      arow = (long)b * 196 + (qq / 7) * 28 + (qq % 7) * 2;
    } else {
      arow = m0 + r;
    }
    eA[rr] = arow * 384 + c8 * 8;
    lAoff[rr] = r * 32 + c8 * 8;
  }
  long eW[2]; int lWoff[2];
#pragma unroll
  for (int rr = 0; rr < 2; ++rr) {
    int r = rr * 32 + rbs;
    eW[rr] = (long)(n0 + r) * 384 + c8 * 8;
    lWoff[rr] = r * 32 + c8 * 8;
  }

  f32x4 acc[4][4] = {};
  const int mrow = lane & 15;
  const int quad = lane >> 4;

  for (int k0 = 0; k0 < 384; k0 += 32) {
    bf16x8 ta[4], tw[2];
#pragma unroll
    for (int rr = 0; rr < 4; ++rr) ta[rr] = *(const bf16x8*)(A + eA[rr] + k0);
#pragma unroll
    for (int rr = 0; rr < 2; ++rr) tw[rr] = *(const bf16x8*)(W + eW[rr] + k0);
    __syncthreads();
#pragma unroll
    for (int rr = 0; rr < 4; ++rr) *(bf16x8*)(As + lAoff[rr]) = ta[rr];
#pragma unroll
    for (int rr = 0; rr < 2; ++rr) *(bf16x8*)(Ws + lWoff[rr]) = tw[rr];
    __syncthreads();

    bf16x8 af[4], bw[4];
#pragma unroll
    for (int mi = 0; mi < 4; ++mi)
      af[mi] = *(const bf16x8*)(As + (wid * 64 + mi * 16 + mrow) * 32 + quad * 8);
#pragma unroll
    for (int ni = 0; ni < 4; ++ni)
      bw[ni] = *(const bf16x8*)(Ws + (ni * 16 + mrow) * 32 + quad * 8);
#pragma unroll
    for (int mi = 0; mi < 4; ++mi)
#pragma unroll
      for (int ni = 0; ni < 4; ++ni)
        acc[mi][ni] = __builtin_amdgcn_mfma_f32_16x16x32_bf16(af[mi], bw[ni], acc[mi][ni], 0, 0, 0);
  }

  // epilogue: C/D layout col=lane&15, row=quad*4+reg (m89-verified)
#pragma unroll
  for (int ni = 0; ni < 4; ++ni) {
    int col = n0 + ni * 16 + mrow;
    float s = sc[col], t = sh[col];
    int h = 0, dd = 0;
    if (EPI == 1) { h = col / 48; dd = col - h * 48; }
    if (EPI == 2) { h = col >> 4; dd = col & 15; }
#pragma unroll
    for (int mi = 0; mi < 4; ++mi) {
#pragma unroll
      for (int reg = 0; reg < 4; ++reg) {
        int m = m0 + wid * 64 + mi * 16 + quad * 4 + reg;
        float y = acc[mi][ni][reg] * s + t;
        if (EPI == 0) {
          ((float*)out)[(long)m * N + col] = y;
        } else if (EPI == 1) {
          int b = m / 196, j = m - b * 196;
          char* base = out + ((long)(b * 12 + h)) * KV2_BLK;
          if (dd < 16) ((bf16*)base)[j * 16 + dd] = (bf16)y;
          else ((bf16*)(base + KV2_VOFF))[(dd - 16) * 196 + j] = (bf16)y;
        } else {
          int b = m / 49, qq = m - b * 49;
          ((bf16*)(out + ((long)(b * 12 + h)) * Q2_BLK))[qq * 16 + dd] = (bf16)y;
        }
      }
    }
  }
}

// ---------------------------------------------------------------------------
// Fused MFMA attention, one block per (b,h). 256 threads (4 waves).
// LDS (42 KB): [vT 14336][q 4096][k 13312]; P (28672) overlays q+k after QK.
__global__ __launch_bounds__(256)
void attn_kernel(const char* __restrict__ kv2, const char* __restrict__ qb2,
                 const float* __restrict__ biasp, bf16* __restrict__ aout) {
  __shared__ __attribute__((aligned(16))) char smem[43008];
  bf16* vT_s = (bf16*)smem;            // [32][224]
  bf16* q_s  = (bf16*)(smem + 14336);  // [64][32]
  bf16* k_s  = (bf16*)(smem + 18432);  // [208][32]
  bf16* P_s  = (bf16*)(smem + 14336);  // [64][224] overlay (post-QK)

  const int bh = blockIdx.x;
  const int b = bh / 12;
  const int h = bh - b * 12;
  const int tid  = threadIdx.x;
  const int lane = tid & 63;
  const int wid  = tid >> 6;

  const bf16* ksrc = (const bf16*)(kv2 + (long)bh * KV2_BLK);
  const bf16* vsrc = (const bf16*)(kv2 + (long)bh * KV2_BLK + KV2_VOFF);
  const bf16* qsrc = (const bf16*)(qb2 + (long)bh * Q2_BLK);

  {
    int row = tid >> 2, cg = tid & 3;
    bf16x8 z = {};
    *(bf16x8*)(q_s + row * 32 + cg * 8) =
        (row < 49 && cg < 2) ? *(const bf16x8*)(qsrc + row * 16 + cg * 8) : z;
    for (int i = tid; i < 832; i += 256) {
      int r = i >> 2, c = i & 3;
      *(bf16x8*)(k_s + r * 32 + c * 8) =
          (r < 196 && c < 2) ? *(const bf16x8*)(ksrc + r * 16 + c * 8) : z;
    }
    bf16x4 z4 = {};
    for (int i = tid; i < 1792; i += 256) {
      int r = i / 56, c = i - r * 56;
      *(bf16x4*)(vT_s + r * 224 + c * 4) =
          (c < 49) ? *(const bf16x4*)(vsrc + r * 196 + c * 4) : z4;
    }
  }
  __syncthreads();

  const int mrow = lane & 15;
  const int quad = lane >> 4;

  // QK^T: 13 n-tiles of 16 keys
  f32x4 s[13];
  bf16x8 aq = *(const bf16x8*)(q_s + (wid * 16 + mrow) * 32 + quad * 8);
#pragma unroll
  for (int jt = 0; jt < 13; ++jt) {
    bf16x8 bk = *(const bf16x8*)(k_s + (jt * 16 + mrow) * 32 + quad * 8);
    f32x4 z = {};
    s[jt] = __builtin_amdgcn_mfma_f32_16x16x32_bf16(aq, bk, z, 0, 0, 0);
  }

  const int rbase = wid * 16 + quad * 4;
#pragma unroll
  for (int jt = 0; jt < 13; ++jt) {
    int c = jt * 16 + mrow;
#pragma unroll
    for (int reg = 0; reg < 4; ++reg) {
      int r = rbase + reg;
      float v = s[jt][reg] * 0.25f;
      if (c < 196) {
        if (r < 49) v += biasp[((long)h * 49 + r) * 196 + c];
      } else {
        v = -1e30f;
      }
      s[jt][reg] = v;
    }
  }
  float mx[4], sm[4];
#pragma unroll
  for (int reg = 0; reg < 4; ++reg) {
    float m = -1e30f;
#pragma unroll
    for (int jt = 0; jt < 13; ++jt) m = fmaxf(m, s[jt][reg]);
    m = fmaxf(m, __shfl_xor(m, 1));
    m = fmaxf(m, __shfl_xor(m, 2));
    m = fmaxf(m, __shfl_xor(m, 4));
    m = fmaxf(m, __shfl_xor(m, 8));
    mx[reg] = m;
  }
#pragma unroll
  for (int jt = 0; jt < 13; ++jt) {
    int c = jt * 16 + mrow;
#pragma unroll
    for (int reg = 0; reg < 4; ++reg)
      s[jt][reg] = (c < 196) ? __expf(s[jt][reg] - mx[reg]) : 0.0f;
  }
#pragma unroll
  for (int reg = 0; reg < 4; ++reg) {
    float t = 0.0f;
#pragma unroll
    for (int jt = 0; jt < 13; ++jt) t += s[jt][reg];
    t += __shfl_xor(t, 1);
    t += __shfl_xor(t, 2);
    t += __shfl_xor(t, 4);
    t += __shfl_xor(t, 8);
    sm[reg] = 1.0f / t;
  }

  __syncthreads();  // all waves done with q_s/k_s before P overlay writes

  bf16* Pw = P_s + wid * 16 * 224;
#pragma unroll
  for (int jt = 0; jt < 13; ++jt) {
#pragma unroll
    for (int reg = 0; reg < 4; ++reg)
      Pw[(quad * 4 + reg) * 224 + jt * 16 + mrow] = (bf16)(s[jt][reg] * sm[reg]);
  }
#pragma unroll
  for (int reg = 0; reg < 4; ++reg)
    Pw[(quad * 4 + reg) * 224 + 208 + mrow] = (bf16)0.0f;

  f32x4 o[2] = {};
#pragma unroll
  for (int kk = 0; kk < 7; ++kk) {
    bf16x8 ap = *(const bf16x8*)(Pw + mrow * 224 + kk * 32 + quad * 8);
#pragma unroll
    for (int nt = 0; nt < 2; ++nt) {
      bf16x8 bv = *(const bf16x8*)(vT_s + (nt * 16 + mrow) * 224 + kk * 32 + quad * 8);
      o[nt] = __builtin_amdgcn_mfma_f32_16x16x32_bf16(ap, bv, o[nt], 0, 0, 0);
    }
  }
#pragma unroll
  for (int nt = 0; nt < 2; ++nt) {
#pragma unroll
    for (int reg = 0; reg < 4; ++reg) {
      int r = rbase + reg;
      if (r < 49) {
        float x = o[nt][reg];
        float sil = x / (1.0f + __expf(-x));
        aout[((long)b * 49 + r) * 384 + h * 32 + nt * 16 + mrow] = (bf16)sil;
      }
    }
  }
}

// ---------------------------------------------------------------------------
extern "C" void kernel_launch(void* const* d_in, const int* in_sizes, int n_in,
                              void* d_out, int out_size, void* d_ws, size_t ws_size,
                              hipStream_t stream) {
  const float* x      = (const float*)d_in[0];
  const float* kv_w   = (const float*)d_in[1];
  const float* q_w    = (const float*)d_in[6];
  const float* pj_w   = (const float*)d_in[11];
  const float* biases = (const float*)d_in[16];
  const int*   bidx   = (const int*)d_in[17];

  char* ws = (char*)d_ws;
  float* scbuf = (float*)ws;                  // 2560 f32
  float* biasp = (float*)(ws + 10256);        // (12,49,196) f32
  char*  qb2   = ws + 471296;                 // 3072 x 1568 B
  bf16*  aout  = (bf16*)(ws + 5288192);       // (12544,384) bf16
  bf16*  xb    = (bf16*)(ws + 14921984);      // (50176,384) bf16 = 38.5 MB
  bf16*  kvwb  = (bf16*)(ws + 53457152);      // (576,384) bf16
  bf16*  qwb   = (bf16*)(ws + 53899520);      // (192,384) bf16
  bf16*  pjwb  = (bf16*)(ws + 54046976);      // (512,384) bf16
  char*  kv2   = ws + 54440192;               // 3072 x 18816 B = 57.8 MB
                                              // end: 112.2 MB (< ~300 MB ws)

  // casts
  cast_kernel<<<9408, 256, 0, stream>>>(x, xb, 19267584L);
  cast_kernel<<<108, 256, 0, stream>>>(kv_w, kvwb, 221184L);
  cast_kernel<<<36, 256, 0, stream>>>(q_w, qwb, 73728L);
  cast_kernel<<<96, 256, 0, stream>>>(pj_w, pjwb, 196608L);

  prep_kernel<<<5, 256, 0, stream>>>(
      (const float*)d_in[2],  (const float*)d_in[3],  (const float*)d_in[4],  (const float*)d_in[5],
      (const float*)d_in[7],  (const float*)d_in[8],  (const float*)d_in[9],  (const float*)d_in[10],
      (const float*)d_in[12], (const float*)d_in[13], (const float*)d_in[14], (const float*)d_in[15],
      scbuf);
  bias_kernel<<<451, 256, 0, stream>>>(biases, bidx, biasp);

  // q = BN(xq @ q_w^T): M=12544 gathered, N=192 (m-major grid)
  gemm_bn_kernel<2, true><<<dim3(98, 3), 128, 0, stream>>>(
      xb, qwb, scbuf + 1152, scbuf + 1344, qb2, 192);

  // kv = BN(x @ kv_w^T): M=50176, N=576 (m-major grid)
  gemm_bn_kernel<1, false><<<dim3(392, 9), 128, 0, stream>>>(
      xb, kvwb, scbuf, scbuf + 576, kv2, 576);

  // fused attention per (b,h)
  attn_kernel<<<3072, 256, 0, stream>>>(kv2, qb2, biasp, aout);

  // out = BN(silu_attn @ pj_w^T): M=12544, N=512, fp32 out (m-major grid)
  gemm_bn_kernel<0, false><<<dim3(98, 8), 128, 0, stream>>>(
      aout, pjwb, scbuf + 1536, scbuf + 2048, (char*)d_out, 512);
}